// Round 1
// baseline (183.177 us; speedup 1.0000x reference)
//
#include <hip/hip_runtime.h>

#define B 4
#define N 4096
#define M 4096
#define C 32
#define TM 256       // m-rows per LDS tile
#define HALF_M 2048  // m per block (m split across 2 blocks)

__device__ __forceinline__ float bf16_to_f32(unsigned short h) {
    unsigned int u = ((unsigned int)h) << 16;
    return __uint_as_float(u);
}

// Main kernel: per (b, n-tile of 64, m-half of 2048), find argmin_m dist.
// Block: 256 threads = 64 n-lanes x 4 m-groups (m interleaved mod 4 so each
// wave's 64 lanes broadcast-read the same LDS y row -> no bank conflicts).
__global__ __launch_bounds__(256, 2)
void nn_main(const void* __restrict__ xptr, const void* __restrict__ yptr,
             const unsigned short* __restrict__ tptr,
             float* __restrict__ wd, int* __restrict__ wi) {
    const bool is_bf16 = (tptr[0] == 0x4120);  // bf16(10.0)=0x4120; f32 low half = 0x0000

    __shared__ float ytile[TM * C];   // 32 KB
    __shared__ float y2s[TM];         // 1 KB
    __shared__ float red_d[4][64];
    __shared__ int   red_i[4][64];

    const int bi   = blockIdx.x;
    const int h    = bi & 1;          // m-half
    const int nt   = (bi >> 1) & 63;  // n-tile
    const int b    = bi >> 7;         // batch
    const int lane = threadIdx.x & 63;
    const int g    = threadIdx.x >> 6;  // m-group == wave id
    const int n    = nt * 64 + lane;

    // ---- load this thread's x row into registers, compute x2 ----
    float xr[C];
    if (is_bf16) {
        const unsigned short* xp = (const unsigned short*)xptr + ((size_t)b * N + n) * C;
        const uint4* xv = (const uint4*)xp;
        #pragma unroll
        for (int i = 0; i < 4; ++i) {
            uint4 v = xv[i];
            unsigned int w0 = v.x, w1 = v.y, w2 = v.z, w3 = v.w;
            xr[i*8+0] = bf16_to_f32((unsigned short)(w0 & 0xffff));
            xr[i*8+1] = bf16_to_f32((unsigned short)(w0 >> 16));
            xr[i*8+2] = bf16_to_f32((unsigned short)(w1 & 0xffff));
            xr[i*8+3] = bf16_to_f32((unsigned short)(w1 >> 16));
            xr[i*8+4] = bf16_to_f32((unsigned short)(w2 & 0xffff));
            xr[i*8+5] = bf16_to_f32((unsigned short)(w2 >> 16));
            xr[i*8+6] = bf16_to_f32((unsigned short)(w3 & 0xffff));
            xr[i*8+7] = bf16_to_f32((unsigned short)(w3 >> 16));
        }
    } else {
        const float4* xv = (const float4*)((const float*)xptr + ((size_t)b * N + n) * C);
        #pragma unroll
        for (int i = 0; i < 8; ++i) {
            float4 v = xv[i];
            xr[i*4+0] = v.x; xr[i*4+1] = v.y; xr[i*4+2] = v.z; xr[i*4+3] = v.w;
        }
    }
    float x2 = 0.f;
    #pragma unroll
    for (int k = 0; k < C; ++k) x2 = fmaf(xr[k], xr[k], x2);

    float best = __builtin_inff();
    int   bidx = 0;

    for (int t0 = 0; t0 < HALF_M; t0 += TM) {
        __syncthreads();
        // ---- stage: thread r loads y row (t0 + r), computes its norm ----
        {
            const int r = threadIdx.x;
            const size_t mg = (size_t)b * M + (size_t)h * HALF_M + t0 + r;
            float yr[C];
            if (is_bf16) {
                const uint4* yv = (const uint4*)((const unsigned short*)yptr + mg * C);
                #pragma unroll
                for (int i = 0; i < 4; ++i) {
                    uint4 v = yv[i];
                    unsigned int w0 = v.x, w1 = v.y, w2 = v.z, w3 = v.w;
                    yr[i*8+0] = bf16_to_f32((unsigned short)(w0 & 0xffff));
                    yr[i*8+1] = bf16_to_f32((unsigned short)(w0 >> 16));
                    yr[i*8+2] = bf16_to_f32((unsigned short)(w1 & 0xffff));
                    yr[i*8+3] = bf16_to_f32((unsigned short)(w1 >> 16));
                    yr[i*8+4] = bf16_to_f32((unsigned short)(w2 & 0xffff));
                    yr[i*8+5] = bf16_to_f32((unsigned short)(w2 >> 16));
                    yr[i*8+6] = bf16_to_f32((unsigned short)(w3 & 0xffff));
                    yr[i*8+7] = bf16_to_f32((unsigned short)(w3 >> 16));
                }
            } else {
                const float4* yv = (const float4*)((const float*)yptr + mg * C);
                #pragma unroll
                for (int i = 0; i < 8; ++i) {
                    float4 v = yv[i];
                    yr[i*4+0] = v.x; yr[i*4+1] = v.y; yr[i*4+2] = v.z; yr[i*4+3] = v.w;
                }
            }
            float s = 0.f;
            #pragma unroll
            for (int k = 0; k < C; ++k) s = fmaf(yr[k], yr[k], s);
            #pragma unroll
            for (int k = 0; k < C; ++k) ytile[r * C + k] = yr[k];
            y2s[r] = s;
        }
        __syncthreads();

        // ---- inner: group g scans m = t0 + 4j + g ----
        #pragma unroll 2
        for (int j = 0; j < TM / 4; ++j) {
            const int mr = 4 * j + g;
            const float4* yv = (const float4*)&ytile[mr * C];
            float a0 = 0.f, a1 = 0.f, a2 = 0.f, a3 = 0.f;
            #pragma unroll
            for (int i = 0; i < 8; ++i) {
                float4 v = yv[i];
                a0 = fmaf(xr[i*4+0], v.x, a0);
                a1 = fmaf(xr[i*4+1], v.y, a1);
                a2 = fmaf(xr[i*4+2], v.z, a2);
                a3 = fmaf(xr[i*4+3], v.w, a3);
            }
            const float dot  = (a0 + a1) + (a2 + a3);
            const float tv   = x2 + y2s[mr];
            const float dist = fmaf(-2.f, dot, tv);  // == tv - 2*dot (2*dot exact)
            if (dist < best) { best = dist; bidx = h * HALF_M + t0 + mr; }
        }
    }

    // ---- reduce across the 4 m-groups (lexicographic: dist, then index) ----
    red_d[g][lane] = best;
    red_i[g][lane] = bidx;
    __syncthreads();
    if (threadIdx.x < 64) {
        float d  = red_d[0][lane];
        int   ix = red_i[0][lane];
        #pragma unroll
        for (int gg = 1; gg < 4; ++gg) {
            float d2 = red_d[gg][lane];
            int   i2 = red_i[gg][lane];
            if (d2 < d || (d2 == d && i2 < ix)) { d = d2; ix = i2; }
        }
        const size_t row = (size_t)b * N + n;
        wd[(size_t)h * (B * N) + row] = d;
        wi[(size_t)h * (B * N) + row] = ix;
    }
}

// Combine the two m-half candidates and gather y_c.
__global__ __launch_bounds__(256)
void nn_combine(const float* __restrict__ wd, const int* __restrict__ wi,
                const void* __restrict__ ycptr,
                const unsigned short* __restrict__ tptr,
                void* __restrict__ outptr) {
    const bool is_bf16 = (tptr[0] == 0x4120);
    const int idx = blockIdx.x * blockDim.x + threadIdx.x;  // 0..B*N-1
    if (idx >= B * N) return;
    const int b = idx / N;
    const float d0 = wd[idx];
    const int   i0 = wi[idx];
    const float d1 = wd[B * N + idx];
    const int   i1 = wi[B * N + idx];
    // half0 indices < half1 indices, so on tie prefer i0 (first occurrence).
    const int ix = (d1 < d0) ? i1 : i0;
    const size_t src = ((size_t)b * M + ix) * 3;
    if (is_bf16) {
        const unsigned short* yc = (const unsigned short*)ycptr;
        unsigned short* o = (unsigned short*)outptr;
        o[idx*3+0] = yc[src+0];
        o[idx*3+1] = yc[src+1];
        o[idx*3+2] = yc[src+2];
    } else {
        const float* yc = (const float*)ycptr;
        float* o = (float*)outptr;
        o[idx*3+0] = yc[src+0];
        o[idx*3+1] = yc[src+1];
        o[idx*3+2] = yc[src+2];
    }
}

extern "C" void kernel_launch(void* const* d_in, const int* in_sizes, int n_in,
                              void* d_out, int out_size, void* d_ws, size_t ws_size,
                              hipStream_t stream) {
    const void* x  = d_in[0];
    const void* y  = d_in[1];
    const void* yc = d_in[2];
    const unsigned short* t = (const unsigned short*)d_in[3];

    float* wd = (float*)d_ws;                                   // 2 * B*N floats
    int*   wi = (int*)((char*)d_ws + 2 * (size_t)B * N * sizeof(float));

    nn_main<<<512, 256, 0, stream>>>(x, y, t, wd, wi);
    nn_combine<<<(B * N) / 256, 256, 0, stream>>>(wd, wi, yc, t, d_out);
}

// Round 2
// 177.286 us; speedup vs baseline: 1.0332x; 1.0332x over previous
//
#include <hip/hip_runtime.h>

#define B 4
#define N 4096
#define M 4096
#define C 32
#define BN (B * N)

typedef short bf16x8 __attribute__((ext_vector_type(8)));  // 8 bf16 in 4 VGPRs
typedef float f32x4  __attribute__((ext_vector_type(4)));

__device__ __forceinline__ float bf16lo(unsigned int u) { return __uint_as_float(u << 16); }
__device__ __forceinline__ float bf16hi(unsigned int u) { return __uint_as_float(u & 0xffff0000u); }
__device__ __forceinline__ float bf16_to_f32(unsigned short h) {
    return __uint_as_float(((unsigned int)h) << 16);
}

// Grid: 512 blocks, 256 threads.
// bf16 path:  bi -> ms = bi&7 (m-split of 512), nb = (bi>>3)&15 (256 n rows), b = bi>>7.
//             Each wave: 64 n rows (4 MFMA tiles), scans 512 m via 32 MFMA m-tiles.
//             Key = dot - y2/2 (argmax == argmin dist; x2 cancels). C-operand seeds -y2/2.
// f32 path:   round-1 VALU kernel (bi -> h = bi&1, nt=(bi>>1)&63, b=bi>>7), writes -dist.
__global__ __launch_bounds__(256, 2)
void nn_main(const void* __restrict__ xptr, const void* __restrict__ yptr,
             const unsigned short* __restrict__ tptr,
             float* __restrict__ wD, int* __restrict__ wI) {
    const bool is_bf16 = (tptr[0] == 0x4120);  // bf16(10.0)=0x4120; f32 low half = 0x0000

    __shared__ float y2s[512];          // bf16 path: -0.5*y2 for this m-split
    __shared__ float ytile[256 * C];    // f32 path
    __shared__ float y2f[256];          // f32 path
    __shared__ float red_d[4][64];      // f32 path
    __shared__ int   red_i[4][64];      // f32 path

    const int tid  = threadIdx.x;
    const int lane = tid & 63;
    const int bi   = blockIdx.x;

    if (is_bf16) {
        const int wv   = tid >> 6;
        const int col  = lane & 15;
        const int quad = lane >> 4;
        const int ms   = bi & 7;
        const int nb   = (bi >> 3) & 15;
        const int b    = bi >> 7;

        const unsigned short* yp = (const unsigned short*)yptr;
        const unsigned short* xp = (const unsigned short*)xptr;

        // ---- stage -0.5*y2 for the 512 m rows of this split ----
        for (int r = tid; r < 512; r += 256) {
            const int m = ms * 512 + r;
            const uint4* p = (const uint4*)(yp + ((size_t)b * M + m) * C);
            float s = 0.f;
            #pragma unroll
            for (int i = 0; i < 4; ++i) {
                uint4 v = p[i];
                float f;
                f = bf16lo(v.x); s = fmaf(f, f, s); f = bf16hi(v.x); s = fmaf(f, f, s);
                f = bf16lo(v.y); s = fmaf(f, f, s); f = bf16hi(v.y); s = fmaf(f, f, s);
                f = bf16lo(v.z); s = fmaf(f, f, s); f = bf16hi(v.z); s = fmaf(f, f, s);
                f = bf16lo(v.w); s = fmaf(f, f, s); f = bf16hi(v.w); s = fmaf(f, f, s);
            }
            y2s[r] = -0.5f * s;
        }
        __syncthreads();

        // ---- A fragments: 4 n-tiles per wave; lane holds X[n=base+col][quad*8 .. +7] ----
        const int n_base = nb * 256 + wv * 64;
        bf16x8 af[4];
        #pragma unroll
        for (int t = 0; t < 4; ++t)
            af[t] = *(const bf16x8*)(xp + ((size_t)b * N + n_base + t * 16 + col) * C + quad * 8);

        float bD[4][4];
        int   bI[4][4];
        #pragma unroll
        for (int t = 0; t < 4; ++t)
            #pragma unroll
            for (int r = 0; r < 4; ++r) { bD[t][r] = -__builtin_inff(); bI[t][r] = 0; }

        const unsigned short* yb = yp + ((size_t)b * M + ms * 512) * C;

        bf16x8 bfr = *(const bf16x8*)(yb + (size_t)col * C + quad * 8);
        for (int mt = 0; mt < 32; ++mt) {
            bf16x8 bnx = bfr;
            if (mt < 31)
                bnx = *(const bf16x8*)(yb + (size_t)((mt + 1) * 16 + col) * C + quad * 8);
            const float y2c  = y2s[mt * 16 + col];
            const int   mcur = ms * 512 + mt * 16 + col;   // col == this lane's m column
            #pragma unroll
            for (int t = 0; t < 4; ++t) {
                f32x4 acc = {y2c, y2c, y2c, y2c};
                acc = __builtin_amdgcn_mfma_f32_16x16x32_bf16(af[t], bfr, acc, 0, 0, 0);
                #pragma unroll
                for (int r = 0; r < 4; ++r) {
                    if (acc[r] > bD[t][r]) { bD[t][r] = acc[r]; bI[t][r] = mcur; }
                }
            }
            bfr = bnx;
        }

        // ---- butterfly over the 16 col-classes (lanes quad*16 + 0..15) ----
        #pragma unroll
        for (int mask = 1; mask < 16; mask <<= 1) {
            #pragma unroll
            for (int t = 0; t < 4; ++t)
                #pragma unroll
                for (int r = 0; r < 4; ++r) {
                    float oD = __shfl_xor(bD[t][r], mask, 64);
                    int   oI = __shfl_xor(bI[t][r], mask, 64);
                    if (oD > bD[t][r] || (oD == bD[t][r] && oI < bI[t][r])) {
                        bD[t][r] = oD; bI[t][r] = oI;
                    }
                }
        }

        // tracker (t,r) of lane-group quad holds row n_base + t*16 + quad*4 + r
        if (col == 0) {
            #pragma unroll
            for (int t = 0; t < 4; ++t)
                #pragma unroll
                for (int r = 0; r < 4; ++r) {
                    const int n = n_base + t * 16 + quad * 4 + r;
                    const size_t g = (size_t)ms * BN + (size_t)b * N + n;
                    wD[g] = bD[t][r];
                    wI[g] = bI[t][r];
                }
        }
    } else {
        // ================= f32 fallback (round-1 kernel, writes -dist keys) ==========
        const int h    = bi & 1;
        const int nt   = (bi >> 1) & 63;
        const int b    = bi >> 7;
        const int g    = tid >> 6;
        const int n    = nt * 64 + lane;
        const int HALF = 2048;

        float xr[C];
        const float4* xv = (const float4*)((const float*)xptr + ((size_t)b * N + n) * C);
        #pragma unroll
        for (int i = 0; i < 8; ++i) {
            float4 v = xv[i];
            xr[i*4+0] = v.x; xr[i*4+1] = v.y; xr[i*4+2] = v.z; xr[i*4+3] = v.w;
        }
        float x2 = 0.f;
        #pragma unroll
        for (int k = 0; k < C; ++k) x2 = fmaf(xr[k], xr[k], x2);

        float best = __builtin_inff();
        int   bidx = 0;

        for (int t0 = 0; t0 < HALF; t0 += 256) {
            __syncthreads();
            {
                const int r = tid;
                const size_t mg = (size_t)b * M + (size_t)h * HALF + t0 + r;
                float yr[C];
                const float4* yv = (const float4*)((const float*)yptr + mg * C);
                #pragma unroll
                for (int i = 0; i < 8; ++i) {
                    float4 v = yv[i];
                    yr[i*4+0] = v.x; yr[i*4+1] = v.y; yr[i*4+2] = v.z; yr[i*4+3] = v.w;
                }
                float s = 0.f;
                #pragma unroll
                for (int k = 0; k < C; ++k) s = fmaf(yr[k], yr[k], s);
                #pragma unroll
                for (int k = 0; k < C; ++k) ytile[r * C + k] = yr[k];
                y2f[r] = s;
            }
            __syncthreads();

            #pragma unroll 2
            for (int j = 0; j < 64; ++j) {
                const int mr = 4 * j + g;
                const float4* yv = (const float4*)&ytile[mr * C];
                float a0 = 0.f, a1 = 0.f, a2 = 0.f, a3 = 0.f;
                #pragma unroll
                for (int i = 0; i < 8; ++i) {
                    float4 v = yv[i];
                    a0 = fmaf(xr[i*4+0], v.x, a0);
                    a1 = fmaf(xr[i*4+1], v.y, a1);
                    a2 = fmaf(xr[i*4+2], v.z, a2);
                    a3 = fmaf(xr[i*4+3], v.w, a3);
                }
                const float dot  = (a0 + a1) + (a2 + a3);
                const float tv   = x2 + y2f[mr];
                const float dist = fmaf(-2.f, dot, tv);
                if (dist < best) { best = dist; bidx = h * HALF + t0 + mr; }
            }
        }

        red_d[g][lane] = best;
        red_i[g][lane] = bidx;
        __syncthreads();
        if (tid < 64) {
            float d  = red_d[0][lane];
            int   ix = red_i[0][lane];
            #pragma unroll
            for (int gg = 1; gg < 4; ++gg) {
                float d2 = red_d[gg][lane];
                int   i2 = red_i[gg][lane];
                if (d2 < d || (d2 == d && i2 < ix)) { d = d2; ix = i2; }
            }
            const size_t row = (size_t)b * N + n;
            wD[(size_t)h * BN + row] = -d;   // negate: combiner is unified argmax
            wI[(size_t)h * BN + row] = ix;
        }
    }
}

// Combine candidate slots (8 for bf16 path, 2 for f32 path) and gather y_c.
__global__ __launch_bounds__(256)
void nn_combine(const float* __restrict__ wD, const int* __restrict__ wI,
                const void* __restrict__ ycptr,
                const unsigned short* __restrict__ tptr,
                void* __restrict__ outptr) {
    const bool is_bf16 = (tptr[0] == 0x4120);
    const int i = blockIdx.x * 256 + threadIdx.x;
    if (i >= BN) return;
    const int b = i >> 12;  // N = 4096
    const int cnt = is_bf16 ? 8 : 2;

    float bk = wD[i];
    int   bx = wI[i];
    for (int s = 1; s < cnt; ++s) {
        const float k  = wD[(size_t)s * BN + i];
        const int   ix = wI[(size_t)s * BN + i];
        if (k > bk || (k == bk && ix < bx)) { bk = k; bx = ix; }
    }

    const size_t src = ((size_t)b * M + bx) * 3;
    if (is_bf16) {
        const unsigned short* yc = (const unsigned short*)ycptr;
        unsigned short* o = (unsigned short*)outptr;
        o[i*3+0] = yc[src+0];
        o[i*3+1] = yc[src+1];
        o[i*3+2] = yc[src+2];
    } else {
        const float* yc = (const float*)ycptr;
        float* o = (float*)outptr;
        o[i*3+0] = yc[src+0];
        o[i*3+1] = yc[src+1];
        o[i*3+2] = yc[src+2];
    }
}

extern "C" void kernel_launch(void* const* d_in, const int* in_sizes, int n_in,
                              void* d_out, int out_size, void* d_ws, size_t ws_size,
                              hipStream_t stream) {
    const void* x  = d_in[0];
    const void* y  = d_in[1];
    const void* yc = d_in[2];
    const unsigned short* t = (const unsigned short*)d_in[3];

    float* wD = (float*)d_ws;                                    // 8 * BN floats
    int*   wI = (int*)((char*)d_ws + (size_t)8 * BN * sizeof(float));

    nn_main<<<512, 256, 0, stream>>>(x, y, t, wD, wI);
    nn_combine<<<(BN + 255) / 256, 256, 0, stream>>>(wD, wI, yc, t, d_out);
}